// Round 10
// baseline (165.618 us; speedup 1.0000x reference)
//
#include <hip/hip_runtime.h>

// SMPL forward, all I/O fp32. B=512, V=6890, J=24, NS=10, NP=207.
//
// Full path (ws >= 10.38MB), 2 launches:
//  k_prep  : partitioned grid: [0,192) jreg partial folds; [192,2460) posedirs->BT bf16;
//            [2460,2487) weights->WT bf16
//  k_fused2: per block (32 batches x 256 verts): inline Rodrigues+chain+G in LDS,
//            A1/A2 fragments in LDS, B-register-resident MFMA GEMM1+GEMM2 + epilogue
// Fallback (small ws): k_prep(jreg) + k_chain + round-2 fused k_main.

#define BN 512
#define NV 6890
#define NVP 6912        // padded V (216 x 32)
#define NJ 24
#define NS 10
#define NP 207
#define PSTR 208
#define KP 224          // padded K for GEMM1 (207 pf + 10 shapes + 7 pad)
#define BB 8
#define TV 256

// fallback ws layout (float offsets)
#define WS_JSP 0                      // 24*8*33 = 6336
#define WS_G   6400                   // 512*288 (fallback only)
#define WS_PF  153856                 // 512*208 (fallback only)
// full-path u16 offsets (after JSP region)
#define WS_WT  324096                 // 4*6912*8  = 221184 -> 545280
#define WS_BT  545280                 // 3*28*6912*8 = 4644864 -> 5190144 u16
#define FULL_NEED ((size_t)10380288)

typedef unsigned short u16;
typedef short bf16x8 __attribute__((ext_vector_type(8)));
typedef float f32x4  __attribute__((ext_vector_type(4)));

__constant__ int c_par[NJ] = {-1,0,0,0,1,2,3,4,5,6,7,8,9,9,9,12,13,14,16,17,18,19,20,21};

__device__ __forceinline__ u16 f2bf(float f){
    union { float f; unsigned i; } x; x.f = f;
    unsigned r = x.i + 0x7fffu + ((x.i >> 16) & 1u);   // RNE
    return (u16)(r >> 16);
}

// ---------------- k_prep: jreg partials (192) | BT conv (2268) | WT conv (27) ----------------
__global__ __launch_bounds__(256) void k_prep(const float* __restrict__ jreg,
                                              const float* __restrict__ vt,
                                              const float* __restrict__ sd,
                                              const float* __restrict__ pd,
                                              const float* __restrict__ wts,
                                              float* __restrict__ ws,
                                              u16* __restrict__ bt,
                                              u16* __restrict__ wt,
                                              int full){
    __shared__ __align__(16) float s_red[4][33];
    __shared__ __align__(16) u16 s_tile[32][65];
    int bid = blockIdx.x;
    int t = threadIdx.x;

    if(bid < 192){
        int j = bid >> 3, s = bid & 7;
        int v0 = s*864, v1 = min(NV, v0+864);
        float acc[33];
        #pragma unroll
        for(int k=0;k<33;k++) acc[k]=0.f;
        for(int v=v0+t; v<v1; v+=256){
            float jr = jreg[j*NV+v];
            #pragma unroll
            for(int d=0;d<3;d++) acc[d] = fmaf(jr, vt[v*3+d], acc[d]);
            const float2* sp = (const float2*)(sd + (size_t)v*30);
            #pragma unroll
            for(int k=0;k<15;k++){
                float2 s2 = sp[k];
                acc[3+2*k]   = fmaf(jr, s2.x, acc[3+2*k]);
                acc[3+2*k+1] = fmaf(jr, s2.y, acc[3+2*k+1]);
            }
        }
        int lane = t & 63, wv = t >> 6;
        #pragma unroll
        for(int k=0;k<33;k++){
            float val = acc[k];
            #pragma unroll
            for(int off=32; off; off>>=1) val += __shfl_down(val, off, 64);
            if(lane==0) s_red[wv][k]=val;
        }
        __syncthreads();
        if(t<33) ws[WS_JSP + (j*8+s)*33 + t] = s_red[0][t]+s_red[1][t]+s_red[2][t]+s_red[3][t];
    } else if(bid < 2460){
        if(!full) return;
        int bid2 = bid - 192;
        int n0 = (bid2 % 324) * 64;
        int k0 = (bid2 / 324) * 32;
        int nl = t & 63, kb = (t>>6)*8;
        int n = n0 + nl;
        #pragma unroll
        for(int i=0;i<8;i++){
            int k = k0 + kb + i;
            float v = 0.f;
            if(n < NV*3){
                if(k < NP)           v = pd[(size_t)k*(NV*3) + n];
                else if(k < NP+NS)   v = sd[(size_t)(n/3)*30 + (n%3)*10 + (k-NP)];
            }
            s_tile[kb+i][nl] = f2bf(v);
        }
        __syncthreads();
        int nl2 = t >> 2, kc = t & 3;
        union { u16 s[8]; uint4 q; } u;
        #pragma unroll
        for(int i=0;i<8;i++) u.s[i] = s_tile[kc*8+i][nl2];
        int ng = n0 + nl2;
        int v = ng/3, d = ng%3;
        int chunk = (k0>>3) + kc;
        *(uint4*)(bt + (((size_t)d*28 + chunk)*NVP + v)*8) = u.q;
    } else {
        if(!full) return;
        int v = (bid - 2460)*256 + t;
        if(v >= NVP) return;
        union { u16 s[32]; uint4 q[4]; } u;
        #pragma unroll
        for(int j=0;j<24;j++) u.s[j] = (v<NV) ? f2bf(wts[(size_t)v*24+j]) : (u16)0;
        #pragma unroll
        for(int j=24;j<32;j++) u.s[j]=0;
        #pragma unroll
        for(int c=0;c<4;c++)
            *(uint4*)(wt + ((size_t)c*NVP + v)*8) = u.q[c];
    }
}

// ---------------- k_fused2: inline chain + GEMM1 + GEMM2 + epilogue ----------------
// grid (16, 27): block = 32 batches (m) x 256 verts (v). LDS ~114.6 KB -> 1 block/CU.
__global__ __launch_bounds__(256) void k_fused2(const float* __restrict__ poses,
                                                const float* __restrict__ shapes,
                                                const float* __restrict__ Rh,
                                                const float* __restrict__ th,
                                                const float* __restrict__ vt,
                                                const float* __restrict__ ws,
                                                const u16* __restrict__ WT,
                                                const u16* __restrict__ BT,
                                                float* __restrict__ out){
    __shared__ float js[792];
    __shared__ float Rl[32*226];           // [b][j<25][9], stride 226
    __shared__ float jre[32*73];           // [b][j<24][3], stride 73
    __shared__ float ch[32*289];           // [b][j<24][12], stride 289
    __shared__ __align__(16) u16 A1L[28*32*8];     // [chunk][b][8]
    __shared__ __align__(16) u16 A2L[12*4*32*8];   // [e][chunk][b][8]

    int t = threadIdx.x;
    int m0 = blockIdx.x * 32;

    // fold partials -> js
    for(int idx=t; idx<792; idx+=256){
        int j = idx/33, e = idx%33;
        float a = 0.f;
        #pragma unroll
        for(int s=0;s<8;s++) a += ws[WS_JSP + (j*8+s)*33 + e];
        js[idx]=a;
    }
    // Rodrigues for 32 batches x 25 joints
    for(int it=t; it<32*25; it+=256){
        int b = it & 31, j = it >> 5;
        int gb = m0 + b;
        float x,y,z;
        if(j<24){ x=poses[gb*72+j*3]; y=poses[gb*72+j*3+1]; z=poses[gb*72+j*3+2]; }
        else    { x=Rh[gb*3];         y=Rh[gb*3+1];         z=Rh[gb*3+2]; }
        float ax=x+1e-8f, ay=y+1e-8f, az=z+1e-8f;
        float ang = sqrtf(ax*ax+ay*ay+az*az);
        float inv = 1.f/ang;
        float rx=x*inv, ry=y*inv, rz=z*inv;
        float s = sinf(ang), c = cosf(ang), oc = 1.f - c;
        float* R = &Rl[b*226 + j*9];
        R[0]=1.f+oc*(-rz*rz-ry*ry); R[1]=-s*rz+oc*(rx*ry);      R[2]= s*ry+oc*(rx*rz);
        R[3]= s*rz+oc*(rx*ry);      R[4]=1.f+oc*(-rz*rz-rx*rx); R[5]=-s*rx+oc*(ry*rz);
        R[6]=-s*ry+oc*(rx*rz);      R[7]= s*rx+oc*(ry*rz);      R[8]=1.f+oc*(-ry*ry-rx*rx);
    }
    __syncthreads();
    // A1L = bf16 [pf | shapes | 0]
    for(int it=t; it<32*224; it+=256){
        int b = it & 31, idx = it >> 5;
        float v = 0.f;
        if(idx<NP){
            int j = 1 + idx/9, e = idx%9;
            v = Rl[b*226 + j*9 + e] - ((e==0||e==4||e==8)?1.f:0.f);
        } else if(idx<NP+NS) v = shapes[(m0+b)*NS + idx-NP];
        A1L[(idx>>3)*256 + b*8 + (idx&7)] = f2bf(v);
    }
    // jrest = JT + JS @ sh
    for(int it=t; it<32*72; it+=256){
        int b = it & 31, rest = it >> 5;
        int j = rest/3, d = rest%3;
        float a = js[j*33 + d];
        #pragma unroll
        for(int l=0;l<NS;l++) a = fmaf(shapes[(m0+b)*NS+l], js[j*33 + 3 + d*10 + l], a);
        jre[b*73 + j*3 + d] = a;
    }
    __syncthreads();
    // chain init (joint 0) -- strided: 384 items > 256 threads
    for(int it=t; it<32*12; it+=256){
        int b = it & 31, e = it >> 5;
        int r = e>>2, c = e&3;
        ch[b*289 + e] = (c<3) ? Rl[b*226 + r*3 + c] : jre[b*73 + r];
    }
    __syncthreads();
    for(int i=1;i<NJ;i++){
        int p = c_par[i];
        for(int it=t; it<32*12; it+=256){
            int b = it & 31, e = it >> 5;
            int r = e>>2, c = e&3;
            const float* cp = &ch[b*289 + p*12 + r*4];
            float acc;
            if(c<3){
                const float* Ri = &Rl[b*226 + i*9];
                acc = cp[0]*Ri[c] + cp[1]*Ri[3+c] + cp[2]*Ri[6+c];
            } else {
                const float* ji = &jre[b*73 + i*3];
                const float* jp = &jre[b*73 + p*3];
                acc = cp[0]*(ji[0]-jp[0]) + cp[1]*(ji[1]-jp[1]) + cp[2]*(ji[2]-jp[2]) + cp[3];
            }
            ch[b*289 + i*12 + e] = acc;
        }
        __syncthreads();
    }
    // G = rot_global * [chR | chT - chR*jrest] -> A2L bf16
    for(int it=t; it<32*32; it+=256){
        int b = it & 31, j = it >> 5;
        if(j < NJ){
            const float* rg = &Rl[b*226 + 24*9];
            const float* cj = &ch[b*289 + j*12];
            const float* jj = &jre[b*73 + j*3];
            float at[3];
            #pragma unroll
            for(int r=0;r<3;r++)
                at[r] = cj[r*4+3] - (cj[r*4+0]*jj[0] + cj[r*4+1]*jj[1] + cj[r*4+2]*jj[2]);
            #pragma unroll
            for(int r=0;r<3;r++){
                #pragma unroll
                for(int c=0;c<3;c++){
                    float g = rg[r*3+0]*cj[0*4+c] + rg[r*3+1]*cj[1*4+c] + rg[r*3+2]*cj[2*4+c];
                    A2L[(r*4+c)*1024 + (j>>3)*256 + b*8 + (j&7)] = f2bf(g);
                }
                float g3 = rg[r*3+0]*at[0] + rg[r*3+1]*at[1] + rg[r*3+2]*at[2];
                A2L[(r*4+3)*1024 + (j>>3)*256 + b*8 + (j&7)] = f2bf(g3);
            }
        } else {
            #pragma unroll
            for(int e=0;e<12;e++)
                A2L[e*1024 + 3*256 + b*8 + (j&7)] = 0;
        }
    }
    __syncthreads();

    // ---- GEMM phase ----
    int w = t>>6, lane = t&63, quad = lane>>4, l16 = lane&15;
    f32x4 zz = {0.f,0.f,0.f,0.f};
    #pragma unroll 1
    for(int vi=0; vi<4; vi++){
        int v = blockIdx.y*256 + vi*64 + w*16 + l16;
        bf16x8 Bf[3][7];
        #pragma unroll
        for(int d=0;d<3;d++)
            #pragma unroll
            for(int s=0;s<7;s++)
                Bf[d][s] = *(const bf16x8*)(BT + (((size_t)d*28 + s*4 + quad)*NVP + v)*8);
        bf16x8 wf = *(const bf16x8*)(WT + ((size_t)quad*NVP + v)*8);
        float vt0=0.f, vt1=0.f, vt2=0.f;
        bool vok = (v < NV);
        if(vok){ vt0=vt[v*3]; vt1=vt[v*3+1]; vt2=vt[v*3+2]; }

        #pragma unroll
        for(int mi=0;mi<2;mi++){
            int mloc = mi*16 + l16;
            f32x4 accP0=zz, accP1=zz, accP2=zz;
            #pragma unroll
            for(int s=0;s<7;s++){
                bf16x8 af = *(const bf16x8*)&A1L[(s*4+quad)*256 + mloc*8];
                accP0 = __builtin_amdgcn_mfma_f32_16x16x32_bf16(af, Bf[0][s], accP0, 0,0,0);
                accP1 = __builtin_amdgcn_mfma_f32_16x16x32_bf16(af, Bf[1][s], accP1, 0,0,0);
                accP2 = __builtin_amdgcn_mfma_f32_16x16x32_bf16(af, Bf[2][s], accP2, 0,0,0);
            }
            f32x4 accT[12];
            #pragma unroll
            for(int e=0;e<12;e++){
                bf16x8 gf = *(const bf16x8*)&A2L[e*1024 + quad*256 + mloc*8];
                accT[e] = __builtin_amdgcn_mfma_f32_16x16x32_bf16(gf, wf, zz, 0,0,0);
            }
            if(vok){
                #pragma unroll
                for(int r=0;r<4;r++){
                    int b = m0 + mi*16 + quad*4 + r;
                    float t0 = th[b*3+0], t1 = th[b*3+1], t2 = th[b*3+2];
                    float p0 = accP0[r] + vt0;
                    float p1 = accP1[r] + vt1;
                    float p2 = accP2[r] + vt2;
                    float o0 = fmaf(accT[0][r],p0, fmaf(accT[1][r],p1, fmaf(accT[2][r], p2, accT[3][r]))) + t0;
                    float o1 = fmaf(accT[4][r],p0, fmaf(accT[5][r],p1, fmaf(accT[6][r], p2, accT[7][r]))) + t1;
                    float o2 = fmaf(accT[8][r],p0, fmaf(accT[9][r],p1, fmaf(accT[10][r],p2, accT[11][r]))) + t2;
                    float* op = out + ((size_t)b*NV + v)*3;
                    op[0]=o0; op[1]=o1; op[2]=o2;
                }
            }
        }
    }
}

// ---------------- fallback: k_chain + k_main (round-2 path) ----------------
__global__ __launch_bounds__(64) void k_chain(const float* __restrict__ poses,
                                              const float* __restrict__ shapes,
                                              const float* __restrict__ Rh,
                                              float* __restrict__ ws){
    int b = blockIdx.x;
    int t = threadIdx.x;
    __shared__ float R[25][9];
    __shared__ float sh[NS];
    __shared__ float js[792];
    __shared__ float jrest[NJ][3];
    __shared__ float rel[NJ][3];
    __shared__ float chR[NJ][9];
    __shared__ float chT[NJ][3];

    if(t<25){
        float x,y,z;
        if(t<24){ x=poses[b*72+t*3]; y=poses[b*72+t*3+1]; z=poses[b*72+t*3+2]; }
        else    { x=Rh[b*3];         y=Rh[b*3+1];         z=Rh[b*3+2]; }
        float ax=x+1e-8f, ay=y+1e-8f, az=z+1e-8f;
        float ang = sqrtf(ax*ax+ay*ay+az*az);
        float inv = 1.f/ang;
        float rx=x*inv, ry=y*inv, rz=z*inv;
        float s = sinf(ang), c = cosf(ang), oc = 1.f - c;
        R[t][0]=1.f+oc*(-rz*rz-ry*ry); R[t][1]=-s*rz+oc*(rx*ry);      R[t][2]= s*ry+oc*(rx*rz);
        R[t][3]= s*rz+oc*(rx*ry);      R[t][4]=1.f+oc*(-rz*rz-rx*rx); R[t][5]=-s*rx+oc*(ry*rz);
        R[t][6]=-s*ry+oc*(rx*rz);      R[t][7]= s*rx+oc*(ry*rz);      R[t][8]=1.f+oc*(-ry*ry-rx*rx);
    }
    if(t<NS) sh[t]=shapes[b*NS+t];
    for(int idx=t; idx<792; idx+=64){
        int j = idx/33, e = idx%33;
        float a = 0.f;
        #pragma unroll
        for(int s=0;s<8;s++) a += ws[WS_JSP + (j*8+s)*33 + e];
        js[idx]=a;
    }
    __syncthreads();
    for(int idx=t; idx<PSTR; idx+=64){
        float v = 0.f;
        if(idx<NP){
            int j = 1 + idx/9, e = idx%9;
            v = R[j][e] - ((e==0||e==4||e==8)?1.f:0.f);
        }
        ws[WS_PF + b*PSTR + idx] = v;
    }
    if(t<NJ){
        #pragma unroll
        for(int d=0;d<3;d++){
            float a = js[t*33 + d];
            #pragma unroll
            for(int l=0;l<NS;l++) a = fmaf(sh[l], js[t*33 + 3 + d*10 + l], a);
            jrest[t][d]=a;
        }
    }
    __syncthreads();
    if(t<NJ){
        int p = c_par[t];
        #pragma unroll
        for(int d=0;d<3;d++) rel[t][d] = (t==0) ? jrest[0][d] : jrest[t][d]-jrest[p][d];
    }
    __syncthreads();
    if(t<9) chR[0][t]=R[0][t];
    if(t<3) chT[0][t]=rel[0][t];
    __syncthreads();
    for(int i=1;i<NJ;i++){
        if(t<12){
            int r=t>>2, cc=t&3, p=c_par[i];
            if(cc<3){
                chR[i][r*3+cc] = chR[p][r*3+0]*R[i][0*3+cc] + chR[p][r*3+1]*R[i][1*3+cc] + chR[p][r*3+2]*R[i][2*3+cc];
            } else {
                chT[i][r] = chR[p][r*3+0]*rel[i][0] + chR[p][r*3+1]*rel[i][1] + chR[p][r*3+2]*rel[i][2] + chT[p][r];
            }
        }
        __syncthreads();
    }
    if(t<NJ){
        float rg[9];
        #pragma unroll
        for(int k=0;k<9;k++) rg[k]=R[24][k];
        float at[3];
        #pragma unroll
        for(int r=0;r<3;r++){
            float tj = chR[t][r*3+0]*jrest[t][0] + chR[t][r*3+1]*jrest[t][1] + chR[t][r*3+2]*jrest[t][2];
            at[r] = chT[t][r] - tj;
        }
        float* g = &ws[WS_G + b*288 + t*12];
        #pragma unroll
        for(int r=0;r<3;r++){
            #pragma unroll
            for(int cc=0;cc<3;cc++)
                g[r*4+cc] = rg[r*3+0]*chR[t][0*3+cc] + rg[r*3+1]*chR[t][1*3+cc] + rg[r*3+2]*chR[t][2*3+cc];
            g[r*4+3] = rg[r*3+0]*at[0] + rg[r*3+1]*at[1] + rg[r*3+2]*at[2];
        }
    }
}

__global__ __launch_bounds__(256) void k_main(const float* __restrict__ vt,
                                              const float* __restrict__ sd,
                                              const float* __restrict__ pd,
                                              const float* __restrict__ wts,
                                              const float* __restrict__ th,
                                              const float* __restrict__ shapes,
                                              const float* __restrict__ ws,
                                              float* __restrict__ out){
    __shared__ __align__(16) float pf_s[BB*PSTR];
    __shared__ __align__(16) float g_s[BB*288];
    __shared__ float th_s[BB*3];
    __shared__ float sh_s[BB*NS];
    int tid = threadIdx.x;
    int b0  = blockIdx.y * BB;
    int v   = blockIdx.x * TV + tid;

    for(int i=tid; i<BB*PSTR; i+=TV) pf_s[i] = ws[WS_PF + b0*PSTR + i];
    for(int i=tid; i<BB*288;  i+=TV) g_s[i]  = ws[WS_G  + b0*288  + i];
    if(tid<BB*3)  th_s[tid] = th[b0*3+tid];
    if(tid<BB*NS) sh_s[tid] = shapes[b0*NS+tid];
    __syncthreads();
    if(v>=NV) return;

    float sdv[30];
    {
        const float2* sp = (const float2*)(sd + (size_t)v*30);
        #pragma unroll
        for(int i=0;i<15;i++){ float2 s2 = sp[i]; sdv[2*i]=s2.x; sdv[2*i+1]=s2.y; }
    }
    float vt0=vt[v*3], vt1=vt[v*3+1], vt2=vt[v*3+2];
    float vp[BB][3];
    #pragma unroll
    for(int b=0;b<BB;b++){
        #pragma unroll
        for(int d=0;d<3;d++){
            float a = (d==0)?vt0:((d==1)?vt1:vt2);
            #pragma unroll
            for(int l=0;l<NS;l++) a = fmaf(sh_s[b*NS+l], sdv[d*10+l], a);
            vp[b][d]=a;
        }
    }
    const float* pcol = pd + (size_t)v*3;
    int p=0;
    for(; p<=NP-4; p+=4){
        float pdv[4][3];
        #pragma unroll
        for(int q=0;q<4;q++){
            size_t base = (size_t)(p+q)*(NV*3);
            pdv[q][0]=pcol[base]; pdv[q][1]=pcol[base+1]; pdv[q][2]=pcol[base+2];
        }
        #pragma unroll
        for(int b=0;b<BB;b++){
            float4 f = *(const float4*)&pf_s[b*PSTR+p];
            #pragma unroll
            for(int d=0;d<3;d++)
                vp[b][d] = fmaf(f.x,pdv[0][d], fmaf(f.y,pdv[1][d], fmaf(f.z,pdv[2][d], fmaf(f.w,pdv[3][d], vp[b][d]))));
        }
    }
    for(; p<NP; p++){
        size_t base=(size_t)p*(NV*3);
        float p0=pcol[base], p1=pcol[base+1], p2=pcol[base+2];
        #pragma unroll
        for(int b=0;b<BB;b++){
            float f = pf_s[b*PSTR+p];
            vp[b][0]=fmaf(f,p0,vp[b][0]); vp[b][1]=fmaf(f,p1,vp[b][1]); vp[b][2]=fmaf(f,p2,vp[b][2]);
        }
    }
    float w[24];
    {
        const float4* wp = (const float4*)(wts + (size_t)v*24);
        #pragma unroll
        for(int i=0;i<6;i++){
            float4 u = wp[i];
            w[i*4+0]=u.x; w[i*4+1]=u.y; w[i*4+2]=u.z; w[i*4+3]=u.w;
        }
    }
    #pragma unroll 1
    for(int b=0;b<BB;b++){
        float4 T0=make_float4(0.f,0.f,0.f,0.f), T1=T0, T2=T0;
        #pragma unroll
        for(int j=0;j<NJ;j++){
            float wj = w[j];
            const float4* g = (const float4*)&g_s[b*288 + j*12];
            float4 g0=g[0], g1=g[1], g2=g[2];
            T0.x=fmaf(wj,g0.x,T0.x); T0.y=fmaf(wj,g0.y,T0.y); T0.z=fmaf(wj,g0.z,T0.z); T0.w=fmaf(wj,g0.w,T0.w);
            T1.x=fmaf(wj,g1.x,T1.x); T1.y=fmaf(wj,g1.y,T1.y); T1.z=fmaf(wj,g1.z,T1.z); T1.w=fmaf(wj,g1.w,T1.w);
            T2.x=fmaf(wj,g2.x,T2.x); T2.y=fmaf(wj,g2.y,T2.y); T2.z=fmaf(wj,g2.z,T2.z); T2.w=fmaf(wj,g2.w,T2.w);
        }
        float x=vp[b][0], y=vp[b][1], z=vp[b][2];
        float ox = fmaf(T0.x,x, fmaf(T0.y,y, fmaf(T0.z,z, T0.w))) + th_s[b*3+0];
        float oy = fmaf(T1.x,x, fmaf(T1.y,y, fmaf(T1.z,z, T1.w))) + th_s[b*3+1];
        float oz = fmaf(T2.x,x, fmaf(T2.y,y, fmaf(T2.z,z, T2.w))) + th_s[b*3+2];
        size_t o = ((size_t)(b0+b)*NV + v)*3;
        out[o]=ox; out[o+1]=oy; out[o+2]=oz;
    }
}

extern "C" void kernel_launch(void* const* d_in, const int* in_sizes, int n_in,
                              void* d_out, int out_size, void* d_ws, size_t ws_size,
                              hipStream_t stream){
    const float* poses  = (const float*)d_in[0];
    const float* shapes = (const float*)d_in[1];
    const float* Rh     = (const float*)d_in[2];
    const float* Th     = (const float*)d_in[3];
    const float* vt     = (const float*)d_in[4];
    const float* sd     = (const float*)d_in[5];
    const float* pdirs  = (const float*)d_in[6];
    const float* jreg   = (const float*)d_in[7];
    const float* wts    = (const float*)d_in[8];
    float* ws  = (float*)d_ws;
    float* out = (float*)d_out;
    u16* u = (u16*)d_ws;
    int full = (ws_size >= FULL_NEED) ? 1 : 0;

    hipLaunchKernelGGL(k_prep, dim3(2487), dim3(256), 0, stream,
                       jreg, vt, sd, pdirs, wts, ws, u + WS_BT, u + WS_WT, full);
    if(full){
        hipLaunchKernelGGL(k_fused2, dim3(BN/32, NVP/256), dim3(256), 0, stream,
                           poses, shapes, Rh, Th, vt, ws, u + WS_WT, u + WS_BT, out);
    } else {
        hipLaunchKernelGGL(k_chain, dim3(BN), dim3(64), 0, stream, poses, shapes, Rh, ws);
        hipLaunchKernelGGL(k_main, dim3((NV+TV-1)/TV, BN/BB), dim3(256), 0, stream,
                           vt, sd, pdirs, wts, Th, shapes, ws, out);
    }
}